// Round 14
// baseline (482.637 us; speedup 1.0000x reference)
//
#include <hip/hip_runtime.h>
#include <hip/hip_bf16.h>

constexpr int Nn   = 100000;
constexpr int Ee   = 1600000;
constexpr int NB   = (Nn + 63) / 64;   // 1563 buckets of 64 nodes
constexpr int BCAP = 1536;             // pair capacity per bucket
constexpr int SCAP = 2048;             // sorted region per bucket (self-loops + pad-to-8)
constexpr int CSTRIDE = 16;            // cursor padding (64B)
constexpr int VPT  = 32;               // edges per thread in k_bucket
constexpr int CBLK = 256 * VPT;        // 8192 edges per block

constexpr int IPROW = 264;             // inproj LDS row pitch (256 + 8 pad)
constexpr int GGROW = 136;             // gat_gemm LDS row pitch (128 + 8 pad)

constexpr float QSCALE = 31.75f;       // int8 encode scale (range ±4)
constexpr float QINV   = 1.0f / 31.75f;
constexpr float CBIAS  = 128.0f * QINV;   // u8-bias correction constant

using bf8 = __attribute__((ext_vector_type(8))) short;   // 8 bf16 (4 VGPRs)
using f4  = __attribute__((ext_vector_type(4))) float;   // MFMA C/D frag

__device__ inline unsigned short f2bfu(float f) {
  __hip_bfloat16 h = __float2bfloat16(f);
  return *reinterpret_cast<unsigned short*>(&h);
}
__device__ inline float bflo(unsigned u) { return __uint_as_float(u << 16); }
__device__ inline float bfhi(unsigned u) { return __uint_as_float(u & 0xffff0000u); }

// ---------------- converts ----------------
__global__ void k_f32_to_bf16(const float* __restrict__ in, __hip_bfloat16* __restrict__ out, long n) {
  long i = (long)blockIdx.x * blockDim.x + threadIdx.x;
  long stride = (long)gridDim.x * blockDim.x;
  for (; i < n; i += stride) out[i] = __float2bfloat16(in[i]);
}

// ---------------- Wext prep: rows 0-127 = W_l; 128-135 = a_src composed; 136-143 = a_dst ----------------
__global__ void k_prepw(const float* __restrict__ gat_W, const float* __restrict__ att_src,
                        const float* __restrict__ att_dst, __hip_bfloat16* __restrict__ Wext) {
  int idx = blockIdx.x * 256 + threadIdx.x;
  if (idx >= 4 * 144 * 128) return;
  int l = idx / (144 * 128);
  int rem = idx % (144 * 128);
  int row = rem / 128, k = rem % 128;
  const float* Wl = gat_W + (long)l * 128 * 128;
  float v;
  if (row < 128) v = Wl[row * 128 + k];
  else if (row < 136) {
    int hh = row - 128; v = 0.f;
    #pragma unroll
    for (int c = 0; c < 16; ++c) v += att_src[l * 128 + hh * 16 + c] * Wl[(hh * 16 + c) * 128 + k];
  } else {
    int hh = row - 136; v = 0.f;
    #pragma unroll
    for (int c = 0; c < 16; ++c) v += att_dst[l * 128 + hh * 16 + c] * Wl[(hh * 16 + c) * 128 + k];
  }
  Wext[(long)l * 144 * 128 + row * 128 + k] = __float2bfloat16(v);
}

// ---------------- init: cursors, sentinel logits, pooledSum ----------------
__global__ void k_init(int* __restrict__ gCursor, int* __restrict__ ovCount,
                       float* __restrict__ pooledSum, float* __restrict__ e_src) {
  int i = blockIdx.x * blockDim.x + threadIdx.x;
  if (i < NB * CSTRIDE) gCursor[i] = 0;
  if (i == 0) *ovCount = 0;
  if (i < 128) pooledSum[i] = 0.f;
  if (i < 8) e_src[Nn * 8 + i] = -1e30f;    // sentinel row: p = exp(leaky(-1e30)) = 0 exactly
}

// ---------------- pass 1: partition edges into 64-node buckets (packed u32: src | dl<<17) ----------------
__global__ __launch_bounds__(256) void k_bucket(
    const int* __restrict__ src, const int* __restrict__ dst,
    int* __restrict__ gCursor, unsigned* __restrict__ pairs,
    int* __restrict__ ovCount, uint2* __restrict__ ovList)
{
  __shared__ int hist[NB];
  int tid = threadIdx.x;
  for (int i = tid; i < NB; i += 256) hist[i] = 0;
  __syncthreads();

  int e0 = blockIdx.x * CBLK + tid;
  int bkt[VPT]; int rnk[VPT];
  #pragma unroll
  for (int r = 0; r < VPT; ++r) {
    int e = e0 + r * 256;
    int b = -1, rk = 0;
    if (e < Ee) { b = dst[e] >> 6; rk = atomicAdd(&hist[b], 1); }
    bkt[r] = b; rnk[r] = rk;
  }
  __syncthreads();
  for (int i = tid; i < NB; i += 256) {
    int c = hist[i];
    if (c > 0) hist[i] = atomicAdd(&gCursor[i * CSTRIDE], c);
  }
  __syncthreads();
  #pragma unroll
  for (int r = 0; r < VPT; ++r) {
    if (bkt[r] >= 0) {
      int e = e0 + r * 256;
      int pos = hist[bkt[r]] + rnk[r];
      if (pos < BCAP) pairs[(long)bkt[r] * BCAP + pos] = (unsigned)src[e] | ((unsigned)(dst[e] & 63) << 17);
      else { int oi = atomicAdd(ovCount, 1); if (oi < 65536) ovList[oi] = make_uint2((unsigned)src[e], (unsigned)dst[e]); }
    }
  }
}

// ---------------- pass 2: per-bucket fine counting-sort in LDS; segments padded to x8 with sentinel ----------------
__global__ __launch_bounds__(256) void k_finesort(
    const unsigned* __restrict__ pairs, const int* __restrict__ gCursor,
    const int* __restrict__ ovCount, const uint2* __restrict__ ovList,
    int* __restrict__ sorted, int* __restrict__ offsets, int* __restrict__ deg)
{
  int b = blockIdx.x;
  int tid = threadIdx.x;
  __shared__ int hist[64];
  __shared__ int lofs[64];
  __shared__ int buf[SCAP];
  __shared__ uint2 ovLoc[64];
  __shared__ int ovLocN, totS;
  if (tid < 64) hist[tid] = 0;
  if (tid == 0) ovLocN = 0;
  for (int i = tid; i < SCAP; i += 256) buf[i] = Nn;   // sentinel prefill (pads)
  __syncthreads();

  int cnt = gCursor[b * CSTRIDE]; if (cnt > BCAP) cnt = BCAP;
  const unsigned* bp = pairs + (long)b * BCAP;

  int mySrc[6], myDl[6], myRk[6];
  #pragma unroll
  for (int j = 0; j < 6; ++j) {
    int i = tid + j * 256;
    int s = -1, dl = 0, rk = 0;
    if (i < cnt) { unsigned p = bp[i]; s = (int)(p & 0x1FFFFu); dl = (int)(p >> 17) & 63; rk = atomicAdd(&hist[dl], 1); }
    mySrc[j] = s; myDl[j] = dl; myRk[j] = rk;
  }
  int ovn = *ovCount;                       // normally 0
  for (int i = tid; i < ovn; i += 256) {
    uint2 p = ovList[i];
    if (((int)p.y >> 6) == b) {
      int dl = (int)p.y & 63;
      int rk = atomicAdd(&hist[dl], 1);
      int li = atomicAdd(&ovLocN, 1);
      if (li < 64) ovLoc[li] = make_uint2(p.x, (unsigned)((rk << 8) | dl));
    }
  }
  __syncthreads();

  if (tid < 64) {
    int v = hist[tid];
    int padLen = (v + 1 + 7) & ~7;           // self-loop + edges, padded to multiple of 8
    int x = padLen;
    #pragma unroll
    for (int o = 1; o < 64; o <<= 1) { int t = __shfl_up(x, o); if (tid >= o) x += t; }
    int lo = x - padLen;                     // exclusive scan of padded lengths
    lofs[tid] = lo;
    int n = b * 64 + tid;
    if (n < Nn) {
      offsets[n] = b * SCAP + lo;
      deg[n] = padLen;
      buf[lo] = n;                           // self-loop in slot 0
    }
    if (tid == 63) totS = x;
  }
  __syncthreads();

  #pragma unroll
  for (int j = 0; j < 6; ++j) {
    if (mySrc[j] >= 0) {
      int pos = lofs[myDl[j]] + 1 + myRk[j];
      if (pos < SCAP) buf[pos] = mySrc[j];
    }
  }
  int ovl = ovLocN; if (ovl > 64) ovl = 64;
  for (int i = tid; i < ovl; i += 256) {
    uint2 p = ovLoc[i];
    int dl = (int)(p.y & 63), rk = (int)(p.y >> 8);
    int pos = lofs[dl] + 1 + rk;
    if (pos < SCAP) buf[pos] = (int)p.x;
  }
  __syncthreads();

  int tot = totS; if (tot > SCAP) tot = SCAP;
  for (int i = tid; i < tot; i += 256) sorted[(long)b * SCAP + i] = buf[i];
}

// ---------------- in_proj (LDS-staged): h_bf = bf16(x @ W_in.T + b_in) ----------------
__global__ __launch_bounds__(512) void k_inproj(
    const float* __restrict__ A, const __hip_bfloat16* __restrict__ W,
    const float* __restrict__ bias, __hip_bfloat16* __restrict__ Cbf)
{
  __shared__ __hip_bfloat16 sA[64 * IPROW];   // 33.8 KB
  int tid = threadIdx.x;
  int bn0 = blockIdx.x * 64;

  #pragma unroll
  for (int pass = 0; pass < 8; ++pass) {
    int idx = pass * 2048 + tid * 4;          // 512 thr x float4 = 2048 floats/pass
    int row = idx >> 8, col = idx & 255;
    int grow = bn0 + row; grow = grow < Nn ? grow : Nn - 1;
    float4 f = *reinterpret_cast<const float4*>(A + (long)grow * 256 + col);
    unsigned p0 = ((unsigned)f2bfu(f.y) << 16) | f2bfu(f.x);
    unsigned p1 = ((unsigned)f2bfu(f.w) << 16) | f2bfu(f.z);
    *reinterpret_cast<uint2*>(reinterpret_cast<unsigned short*>(sA) + row * IPROW + col) = make_uint2(p0, p1);
  }
  __syncthreads();

  int lane = threadIdx.x & 63;
  int w = threadIdx.x >> 6;
  int wr = w >> 2, wc = w & 3;
  int d0 = wc * 32;
  int r = lane & 15, g = lane >> 4;

  f4 acc[2][2] = {};
  #pragma unroll
  for (int k0 = 0; k0 < 256; k0 += 32) {
    bf8 a[2], b[2];
    #pragma unroll
    for (int mi = 0; mi < 2; ++mi)
      a[mi] = *reinterpret_cast<const bf8*>(sA + (wr * 32 + mi * 16 + r) * IPROW + k0 + g * 8);
    #pragma unroll
    for (int ni = 0; ni < 2; ++ni)
      b[ni] = *reinterpret_cast<const bf8*>(W + (long)(d0 + ni * 16 + r) * 256 + k0 + g * 8);
    #pragma unroll
    for (int mi = 0; mi < 2; ++mi)
      #pragma unroll
      for (int ni = 0; ni < 2; ++ni)
        acc[mi][ni] = __builtin_amdgcn_mfma_f32_16x16x32_bf16(a[mi], b[ni], acc[mi][ni], 0, 0, 0);
  }
  int n0 = bn0 + wr * 32;
  #pragma unroll
  for (int mi = 0; mi < 2; ++mi) {
    int nb = n0 + mi * 16 + g * 4;
    #pragma unroll
    for (int ni = 0; ni < 2; ++ni) {
      int d = d0 + ni * 16 + r;
      #pragma unroll
      for (int q = 0; q < 4; ++q) {
        int n = nb + q;
        if (n < Nn) Cbf[(long)n * 128 + d] = __float2bfloat16(acc[mi][ni][q] + bias[d]);
      }
    }
  }
}

// ---------------- layer GEMM (LDS-staged) with fused logits: [xh_u8 | e] = h @ Wext.T ----------------
__global__ __launch_bounds__(640) void k_gat_gemm(
    const __hip_bfloat16* __restrict__ A,     // h_bf [Nn][128]
    const __hip_bfloat16* __restrict__ Wext,  // [144][128]
    unsigned char* __restrict__ xh,           // biased u8 messages: q = clamp(v)*QSCALE + 128
    float* __restrict__ e_src, float* __restrict__ e_dst)
{
  __shared__ __hip_bfloat16 sA[64 * GGROW];   // 17.4 KB
  int tid = threadIdx.x;
  int bn0 = blockIdx.x * 64;

  {   // stage 64x128 bf16 = 1024 x 16B units
    int row = tid >> 4, col = (tid & 15) * 8;
    int grow = bn0 + row; grow = grow < Nn ? grow : Nn - 1;
    uint4 v = *reinterpret_cast<const uint4*>(A + (long)grow * 128 + col);
    *reinterpret_cast<uint4*>(reinterpret_cast<unsigned short*>(sA) + row * GGROW + col) = v;
    if (tid < 384) {
      int u1 = 640 + tid;
      int row1 = u1 >> 4, col1 = (u1 & 15) * 8;
      int grow1 = bn0 + row1; grow1 = grow1 < Nn ? grow1 : Nn - 1;
      uint4 v1 = *reinterpret_cast<const uint4*>(A + (long)grow1 * 128 + col1);
      *reinterpret_cast<uint4*>(reinterpret_cast<unsigned short*>(sA) + row1 * GGROW + col1) = v1;
    }
  }
  __syncthreads();

  int lane = threadIdx.x & 63;
  int w = threadIdx.x >> 6;
  int wr = w / 5, wc = w % 5;
  int d0 = wc * 32;
  int r = lane & 15, g = lane >> 4;
  bool eTile = (wc == 4);

  f4 acc[2][2] = {};
  #pragma unroll
  for (int k0 = 0; k0 < 128; k0 += 32) {
    bf8 a[2], b[2];
    #pragma unroll
    for (int mi = 0; mi < 2; ++mi)
      a[mi] = *reinterpret_cast<const bf8*>(sA + (wr * 32 + mi * 16 + r) * GGROW + k0 + g * 8);
    b[0] = *reinterpret_cast<const bf8*>(Wext + (long)(d0 + r) * 128 + k0 + g * 8);
    if (!eTile) b[1] = *reinterpret_cast<const bf8*>(Wext + (long)(d0 + 16 + r) * 128 + k0 + g * 8);
    #pragma unroll
    for (int mi = 0; mi < 2; ++mi) {
      acc[mi][0] = __builtin_amdgcn_mfma_f32_16x16x32_bf16(a[mi], b[0], acc[mi][0], 0, 0, 0);
      if (!eTile) acc[mi][1] = __builtin_amdgcn_mfma_f32_16x16x32_bf16(a[mi], b[1], acc[mi][1], 0, 0, 0);
    }
  }
  int n0 = bn0 + wr * 32;
  if (!eTile) {
    #pragma unroll
    for (int mi = 0; mi < 2; ++mi) {
      int nb = n0 + mi * 16 + g * 4;
      #pragma unroll
      for (int ni = 0; ni < 2; ++ni) {
        int d = d0 + ni * 16 + r;
        #pragma unroll
        for (int q = 0; q < 4; ++q) {
          int n = nb + q;
          if (n < Nn) {
            float v = fminf(fmaxf(acc[mi][ni][q], -4.f), 4.f);
            xh[(long)n * 128 + d] = (unsigned char)(int)(rintf(v * QSCALE) + 128.f);
          }
        }
      }
    }
  } else {
    #pragma unroll
    for (int mi = 0; mi < 2; ++mi) {
      int nb = n0 + mi * 16 + g * 4;
      #pragma unroll
      for (int q = 0; q < 4; ++q) {
        int n = nb + q;
        if (n < Nn) {
          float v = acc[mi][0][q];
          if (r < 8) e_src[n * 8 + r] = v;
          else       e_dst[n * 8 + (r - 8)] = v;
        }
      }
    }
  }
}

// ---------------- fused agg: 8 ch/lane, uint2 gathers, 4 edges per wave-instruction ----------------
// Lane roles: r = lane&15 covers channels 8r..8r+7; eg = lane>>4 is the edge-in-round.
// p-compute: lane = pe*8+ph computes p[edge pe][head ph] (8 edges x 8 heads per pass,
// two passes per 16-edge block). Sharing via shfl (2 per 4-edge round). Sentinel-guarded.
__global__ __launch_bounds__(256) void k_gat_agg(
    const unsigned char* __restrict__ xh,
    const float* __restrict__ e_src, const float* __restrict__ e_dst,
    const int* __restrict__ offsets, const int* __restrict__ deg, const int* __restrict__ sorted,
    const float* __restrict__ gat_b, const float* __restrict__ ln_g, const float* __restrict__ ln_b,
    float* __restrict__ hOut, __hip_bfloat16* __restrict__ h_bf, int last)
{
  int wv = threadIdx.x >> 6;
  int lane = threadIdx.x & 63;
  int n = blockIdx.x * 4 + wv;
  if (n >= Nn) return;

  int r  = lane & 15;            // channel group: ch 8r..8r+7
  int eg = lane >> 4;            // edge slot within 4-edge round
  int ph = lane & 7;             // p-head
  int pe = lane >> 3;            // p-edge slot (0..7)
  int hd = r >> 1;               // head of my channels

  int beg = offsets[n], len = deg[n];     // len multiple of 8
  float edstP = e_dst[n * 8 + ph];

  const uint2* xq2 = (const uint2*)xh;    // row = 16 uint2
  float sOwn = 0.f;
  float b[8] = {};

  for (int i = 0; i < len; i += 16) {
    int idxA = i + pe, idxB = i + 8 + pe;
    int scA = (idxA < len) ? sorted[beg + idxA] : Nn;
    int scB = (idxB < len) ? sorted[beg + idxB] : Nn;
    float lA = e_src[scA * 8 + ph] + edstP; lA = fmaxf(lA, 0.2f * lA);
    float lB = e_src[scB * 8 + ph] + edstP; lB = fmaxf(lB, 0.2f * lB);
    float pA = __expf(lA), pB = __expf(lB);
    sOwn += pA + pB;

    // share p and row ids for the 4 rounds (edges i+4j+eg)
    float pR[4]; int scR[4];
    #pragma unroll
    for (int j = 0; j < 4; ++j) {
      int e = j * 4 + eg;                  // 0..15
      int slP = ((e & 7) << 3) | hd;       // lane holding p[e][hd]
      int slS = (e & 7) << 3;              // lane holding sc[e]
      pR[j]  = (j < 2) ? __shfl(pA, slP) : __shfl(pB, slP);
      scR[j] = (j < 2) ? __shfl(scA, slS) : __shfl(scB, slS);
    }
    // batched gathers: 4 x uint2 (each instruction fetches 4 rows x 128B)
    uint2 u[4];
    #pragma unroll
    for (int j = 0; j < 4; ++j) u[j] = xq2[(unsigned)scR[j] * 16u + (unsigned)r];
    #pragma unroll
    for (int j = 0; j < 4; ++j) {
      float p = pR[j];
      b[0] += p * (float)(u[j].x & 0xffu);
      b[1] += p * (float)((u[j].x >> 8) & 0xffu);
      b[2] += p * (float)((u[j].x >> 16) & 0xffu);
      b[3] += p * (float)(u[j].x >> 24);
      b[4] += p * (float)(u[j].y & 0xffu);
      b[5] += p * (float)((u[j].y >> 8) & 0xffu);
      b[6] += p * (float)((u[j].y >> 16) & 0xffu);
      b[7] += p * (float)(u[j].y >> 24);
    }
  }

  // s[ph]: sum over pe slots (lane bits 3..5)
  sOwn += __shfl_xor(sOwn, 8);
  sOwn += __shfl_xor(sOwn, 16);
  sOwn += __shfl_xor(sOwn, 32);
  float inv = QINV / (sOwn + 1e-16f);     // lane holds inv for head ph
  float invMine = __shfl(inv, hd);        // lane hd has ph == hd

  // combine the 4 eg groups (each accumulated a disjoint quarter of edges)
  #pragma unroll
  for (int j = 0; j < 8; ++j) { b[j] += __shfl_xor(b[j], 16); b[j] += __shfl_xor(b[j], 32); }

  // epilogue: bias + residual(bf16) + u8-bias correction + LayerNorm (all lanes compute; lane<16 stores)
  int c0 = 8 * r;
  float4 rb0 = *reinterpret_cast<const float4*>(gat_b + c0);
  float4 rb1 = *reinterpret_cast<const float4*>(gat_b + c0 + 4);
  uint4 r4 = ((const uint4*)h_bf)[(long)n * 16 + r];
  float o[8];
  o[0] = b[0] * invMine + rb0.x + bflo(r4.x) - CBIAS;
  o[1] = b[1] * invMine + rb0.y + bfhi(r4.x) - CBIAS;
  o[2] = b[2] * invMine + rb0.z + bflo(r4.y) - CBIAS;
  o[3] = b[3] * invMine + rb0.w + bfhi(r4.y) - CBIAS;
  o[4] = b[4] * invMine + rb1.x + bflo(r4.z) - CBIAS;
  o[5] = b[5] * invMine + rb1.y + bfhi(r4.z) - CBIAS;
  o[6] = b[6] * invMine + rb1.z + bflo(r4.w) - CBIAS;
  o[7] = b[7] * invMine + rb1.w + bfhi(r4.w) - CBIAS;

  float t = o[0] + o[1] + o[2] + o[3] + o[4] + o[5] + o[6] + o[7];
  t += __shfl_xor(t, 1); t += __shfl_xor(t, 2); t += __shfl_xor(t, 4); t += __shfl_xor(t, 8);
  float mean = t * (1.f / 128.f);
  float sq = 0.f;
  float d[8];
  #pragma unroll
  for (int j = 0; j < 8; ++j) { d[j] = o[j] - mean; sq += d[j] * d[j]; }
  sq += __shfl_xor(sq, 1); sq += __shfl_xor(sq, 2); sq += __shfl_xor(sq, 4); sq += __shfl_xor(sq, 8);
  float rstd = rsqrtf(sq * (1.f / 128.f) + 1e-5f);

  float4 g0 = *reinterpret_cast<const float4*>(ln_g + c0);
  float4 g1 = *reinterpret_cast<const float4*>(ln_g + c0 + 4);
  float4 bb0 = *reinterpret_cast<const float4*>(ln_b + c0);
  float4 bb1 = *reinterpret_cast<const float4*>(ln_b + c0 + 4);
  float y[8];
  y[0] = d[0] * rstd * g0.x + bb0.x;
  y[1] = d[1] * rstd * g0.y + bb0.y;
  y[2] = d[2] * rstd * g0.z + bb0.z;
  y[3] = d[3] * rstd * g0.w + bb0.w;
  y[4] = d[4] * rstd * g1.x + bb1.x;
  y[5] = d[5] * rstd * g1.y + bb1.y;
  y[6] = d[6] * rstd * g1.z + bb1.z;
  y[7] = d[7] * rstd * g1.w + bb1.w;

  if (lane < 16) {
    if (last) {
      *reinterpret_cast<float4*>(hOut + (long)n * 128 + c0) = make_float4(y[0], y[1], y[2], y[3]);
      *reinterpret_cast<float4*>(hOut + (long)n * 128 + c0 + 4) = make_float4(y[4], y[5], y[6], y[7]);
    }
    uint4 pk;
    pk.x = ((unsigned)f2bfu(y[1]) << 16) | f2bfu(y[0]);
    pk.y = ((unsigned)f2bfu(y[3]) << 16) | f2bfu(y[2]);
    pk.z = ((unsigned)f2bfu(y[5]) << 16) | f2bfu(y[4]);
    pk.w = ((unsigned)f2bfu(y[7]) << 16) | f2bfu(y[6]);
    ((uint4*)h_bf)[(long)n * 16 + r] = pk;
  }
}

// ---------------- pooling: 256 blocks x 8 waves, uint4 rows, wave+LDS reduce ----------------
__global__ __launch_bounds__(512) void k_pool(const __hip_bfloat16* __restrict__ h_bf, float* __restrict__ pooledSum) {
  int tid = threadIdx.x;
  int wv = tid >> 6, lane = tid & 63;
  int sub = lane >> 4;          // which of 4 rows this wave-iteration
  int c16 = lane & 15;          // 16B chunk within row -> channels 8*c16 .. 8*c16+7
  const uint4* hq = (const uint4*)h_bf;   // row = 16 uint4

  float acc[8] = {};
  for (int row = blockIdx.x * 32 + wv * 4 + sub; row < Nn; row += 256 * 32) {
    uint4 v = hq[(long)row * 16 + c16];
    acc[0] += bflo(v.x); acc[1] += bfhi(v.x);
    acc[2] += bflo(v.y); acc[3] += bfhi(v.y);
    acc[4] += bflo(v.z); acc[5] += bfhi(v.z);
    acc[6] += bflo(v.w); acc[7] += bfhi(v.w);
  }
  #pragma unroll
  for (int j = 0; j < 8; ++j) { acc[j] += __shfl_xor(acc[j], 16); acc[j] += __shfl_xor(acc[j], 32); }

  __shared__ float red[8][128];
  if (lane < 16) {
    #pragma unroll
    for (int j = 0; j < 8; ++j) red[wv][c16 * 8 + j] = acc[j];
  }
  __syncthreads();
  if (tid < 128) {
    float s = 0.f;
    #pragma unroll
    for (int w2 = 0; w2 < 8; ++w2) s += red[w2][tid];
    atomicAdd(&pooledSum[tid], s);
  }
}

__global__ __launch_bounds__(128) void k_final(
    const float* __restrict__ pooledSum,
    const float* __restrict__ W_mu, const float* __restrict__ b_mu,
    const float* __restrict__ W_lv, const float* __restrict__ b_lv,
    float* __restrict__ mu_out, float* __restrict__ lv_out, float* __restrict__ pooled_out)
{
  int d = threadIdx.x;
  __shared__ float pm[128];
  float p = pooledSum[d] * (1.f / (float)Nn);
  pm[d] = p; pooled_out[d] = p;
  __syncthreads();
  float mu = b_mu[d], lv = b_lv[d];
  const float4* wm = reinterpret_cast<const float4*>(W_mu + d * 128);
  const float4* wl = reinterpret_cast<const float4*>(W_lv + d * 128);
  #pragma unroll 8
  for (int c = 0; c < 32; ++c) {
    float4 a = wm[c], b = wl[c];
    float4 p4 = *reinterpret_cast<const float4*>(pm + 4 * c);
    mu += a.x * p4.x + a.y * p4.y + a.z * p4.z + a.w * p4.w;
    lv += b.x * p4.x + b.y * p4.y + b.z * p4.z + b.w * p4.w;
  }
  mu_out[d] = mu; lv_out[d] = lv;
}

// ---------------- launch ----------------
extern "C" void kernel_launch(void* const* d_in, const int* in_sizes, int n_in,
                              void* d_out, int out_size, void* d_ws, size_t ws_size,
                              hipStream_t stream) {
  const float* x      = (const float*)d_in[0];
  const int*   ei     = (const int*)d_in[1];
  const float* W_in   = (const float*)d_in[2];
  const float* b_in   = (const float*)d_in[3];
  const float* gat_W  = (const float*)d_in[4];
  const float* att_src= (const float*)d_in[5];
  const float* att_dst= (const float*)d_in[6];
  const float* gat_b  = (const float*)d_in[7];
  const float* ln_g   = (const float*)d_in[8];
  const float* ln_b   = (const float*)d_in[9];
  const float* W_mu   = (const float*)d_in[10];
  const float* b_mu   = (const float*)d_in[11];
  const float* W_lv   = (const float*)d_in[12];
  const float* b_lv   = (const float*)d_in[13];

  float* out = (float*)d_out;
  float* mu_out = out;
  float* lv_out = out + 128;
  float* h      = out + 256;                       // [Nn x 128] final h lives in d_out
  float* pooled_out = out + 256 + (long)Nn * 128;

  const int* srcE = ei;
  const int* dstE = ei + Ee;

  char* wsb = (char*)d_ws;
  size_t o = 0;
  auto take = [&](size_t bytes) { void* p = wsb + o; o += (bytes + 255) & ~(size_t)255; return p; };
  __hip_bfloat16* h_bf   = (__hip_bfloat16*)take((long)Nn * 128 * 2);
  unsigned char*  xh_u8  = (unsigned char*)take((long)(Nn + 1) * 128);  // 12.8MB (+1 sentinel row); pairs aliases it
  unsigned*       pairs  = (unsigned*)xh_u8;
  float*          e_src  = (float*)take((long)(Nn + 1) * 8 * 4);        // +1 sentinel row (-1e30)
  float*          e_dst  = (float*)take((long)Nn * 8 * 4);
  int*            sorted = (int*)take((long)NB * SCAP * 4);             // 12.8MB padded segments
  int*            offsets= (int*)take((long)Nn * 4);
  int*            deg    = (int*)take((long)Nn * 4);
  int*            gCursor= (int*)take((long)NB * CSTRIDE * 4);
  int*            ovCount= (int*)take(256);
  uint2*          ovList = (uint2*)take(65536L * 8);
  float*          pooledSum = (float*)take(512);
  __hip_bfloat16* Win_bf = (__hip_bfloat16*)take(128L * 256 * 2);
  __hip_bfloat16* Wext   = (__hip_bfloat16*)take(4L * 144 * 128 * 2);
  (void)ws_size; (void)n_in; (void)in_sizes; (void)out_size;

  k_f32_to_bf16<<<64, 256, 0, stream>>>(W_in, Win_bf, 128L * 256);
  k_prepw<<<(4 * 144 * 128 + 255) / 256, 256, 0, stream>>>(gat_W, att_src, att_dst, Wext);

  // CSR build: bucket partition + per-bucket LDS counting sort (padded to x8)
  k_init<<<(NB * CSTRIDE + 255) / 256, 256, 0, stream>>>(gCursor, ovCount, pooledSum, e_src);
  k_bucket<<<(Ee + CBLK - 1) / CBLK, 256, 0, stream>>>(srcE, dstE, gCursor, pairs, ovCount, ovList);
  k_finesort<<<NB, 256, 0, stream>>>(pairs, gCursor, ovCount, ovList, sorted, offsets, deg);

  int gB = (Nn + 63) / 64;   // 1563
  k_inproj<<<gB, 512, 0, stream>>>(x, Win_bf, b_in, h_bf);

  for (int l = 0; l < 4; ++l) {
    k_gat_gemm<<<gB, 640, 0, stream>>>(h_bf, Wext + (long)l * 144 * 128, xh_u8, e_src, e_dst);
    k_gat_agg<<<(Nn + 3) / 4, 256, 0, stream>>>(xh_u8, e_src, e_dst, offsets, deg, sorted,
                                                gat_b + l * 128, ln_g + l * 128, ln_b + l * 128,
                                                h, h_bf, (l == 3) ? 1 : 0);
  }

  k_pool<<<256, 512, 0, stream>>>(h_bf, pooledSum);
  k_final<<<1, 128, 0, stream>>>(pooledSum, W_mu, b_mu, W_lv, b_lv, mu_out, lv_out, pooled_out);
}

// Round 15
// 455.779 us; speedup vs baseline: 1.0589x; 1.0589x over previous
//
#include <hip/hip_runtime.h>
#include <hip/hip_bf16.h>

constexpr int Nn   = 100000;
constexpr int Ee   = 1600000;
constexpr int NB   = (Nn + 63) / 64;   // 1563 buckets of 64 nodes
constexpr int BCAP = 1536;             // pair capacity per bucket
constexpr int SCAP = 2048;             // sorted region per bucket (self-loops + pad-to-8)
constexpr int CSTRIDE = 16;            // cursor padding (64B)
constexpr int VPT  = 32;               // edges per thread in k_bucket
constexpr int CBLK = 256 * VPT;        // 8192 edges per block

constexpr int IPROW = 264;             // inproj LDS row pitch (256 + 8 pad)
constexpr int GGROW = 136;             // gat_gemm LDS row pitch (128 + 8 pad)

constexpr float QSCALE = 31.75f;       // int8 encode scale (range ±4)
constexpr float QINV   = 1.0f / 31.75f;
constexpr float CBIAS  = 128.0f * QINV;   // u8-bias correction constant

using bf8 = __attribute__((ext_vector_type(8))) short;   // 8 bf16 (4 VGPRs)
using f4  = __attribute__((ext_vector_type(4))) float;   // MFMA C/D frag

__device__ inline unsigned short f2bfu(float f) {
  __hip_bfloat16 h = __float2bfloat16(f);
  return *reinterpret_cast<unsigned short*>(&h);
}
__device__ inline float bflo(unsigned u) { return __uint_as_float(u << 16); }
__device__ inline float bfhi(unsigned u) { return __uint_as_float(u & 0xffff0000u); }

// ---------------- converts ----------------
__global__ void k_f32_to_bf16(const float* __restrict__ in, __hip_bfloat16* __restrict__ out, long n) {
  long i = (long)blockIdx.x * blockDim.x + threadIdx.x;
  long stride = (long)gridDim.x * blockDim.x;
  for (; i < n; i += stride) out[i] = __float2bfloat16(in[i]);
}

// ---------------- Wext prep: rows 0-127 = W_l; 128-135 = a_src composed; 136-143 = a_dst ----------------
__global__ void k_prepw(const float* __restrict__ gat_W, const float* __restrict__ att_src,
                        const float* __restrict__ att_dst, __hip_bfloat16* __restrict__ Wext) {
  int idx = blockIdx.x * 256 + threadIdx.x;
  if (idx >= 4 * 144 * 128) return;
  int l = idx / (144 * 128);
  int rem = idx % (144 * 128);
  int row = rem / 128, k = rem % 128;
  const float* Wl = gat_W + (long)l * 128 * 128;
  float v;
  if (row < 128) v = Wl[row * 128 + k];
  else if (row < 136) {
    int hh = row - 128; v = 0.f;
    #pragma unroll
    for (int c = 0; c < 16; ++c) v += att_src[l * 128 + hh * 16 + c] * Wl[(hh * 16 + c) * 128 + k];
  } else {
    int hh = row - 136; v = 0.f;
    #pragma unroll
    for (int c = 0; c < 16; ++c) v += att_dst[l * 128 + hh * 16 + c] * Wl[(hh * 16 + c) * 128 + k];
  }
  Wext[(long)l * 144 * 128 + row * 128 + k] = __float2bfloat16(v);
}

// ---------------- init: cursors, sentinel logits, pooledSum ----------------
__global__ void k_init(int* __restrict__ gCursor, int* __restrict__ ovCount,
                       float* __restrict__ pooledSum, float* __restrict__ e_src) {
  int i = blockIdx.x * blockDim.x + threadIdx.x;
  if (i < NB * CSTRIDE) gCursor[i] = 0;
  if (i == 0) *ovCount = 0;
  if (i < 128) pooledSum[i] = 0.f;
  if (i < 8) e_src[Nn * 8 + i] = -1e30f;    // sentinel row: p = exp(leaky(-1e30)) = 0 exactly
}

// ---------------- pass 1: partition edges into 64-node buckets (packed u32: src | dl<<17) ----------------
__global__ __launch_bounds__(256) void k_bucket(
    const int* __restrict__ src, const int* __restrict__ dst,
    int* __restrict__ gCursor, unsigned* __restrict__ pairs,
    int* __restrict__ ovCount, uint2* __restrict__ ovList)
{
  __shared__ int hist[NB];
  int tid = threadIdx.x;
  for (int i = tid; i < NB; i += 256) hist[i] = 0;
  __syncthreads();

  int e0 = blockIdx.x * CBLK + tid;
  int bkt[VPT]; int rnk[VPT];
  #pragma unroll
  for (int r = 0; r < VPT; ++r) {
    int e = e0 + r * 256;
    int b = -1, rk = 0;
    if (e < Ee) { b = dst[e] >> 6; rk = atomicAdd(&hist[b], 1); }
    bkt[r] = b; rnk[r] = rk;
  }
  __syncthreads();
  for (int i = tid; i < NB; i += 256) {
    int c = hist[i];
    if (c > 0) hist[i] = atomicAdd(&gCursor[i * CSTRIDE], c);
  }
  __syncthreads();
  #pragma unroll
  for (int r = 0; r < VPT; ++r) {
    if (bkt[r] >= 0) {
      int e = e0 + r * 256;
      int pos = hist[bkt[r]] + rnk[r];
      if (pos < BCAP) pairs[(long)bkt[r] * BCAP + pos] = (unsigned)src[e] | ((unsigned)(dst[e] & 63) << 17);
      else { int oi = atomicAdd(ovCount, 1); if (oi < 65536) ovList[oi] = make_uint2((unsigned)src[e], (unsigned)dst[e]); }
    }
  }
}

// ---------------- pass 2: per-bucket fine counting-sort in LDS; segments padded to x8 with sentinel ----------------
__global__ __launch_bounds__(256) void k_finesort(
    const unsigned* __restrict__ pairs, const int* __restrict__ gCursor,
    const int* __restrict__ ovCount, const uint2* __restrict__ ovList,
    int* __restrict__ sorted, int* __restrict__ offsets, int* __restrict__ deg)
{
  int b = blockIdx.x;
  int tid = threadIdx.x;
  __shared__ int hist[64];
  __shared__ int lofs[64];
  __shared__ int buf[SCAP];
  __shared__ uint2 ovLoc[64];
  __shared__ int ovLocN, totS;
  if (tid < 64) hist[tid] = 0;
  if (tid == 0) ovLocN = 0;
  for (int i = tid; i < SCAP; i += 256) buf[i] = Nn;   // sentinel prefill (pads)
  __syncthreads();

  int cnt = gCursor[b * CSTRIDE]; if (cnt > BCAP) cnt = BCAP;
  const unsigned* bp = pairs + (long)b * BCAP;

  int mySrc[6], myDl[6], myRk[6];
  #pragma unroll
  for (int j = 0; j < 6; ++j) {
    int i = tid + j * 256;
    int s = -1, dl = 0, rk = 0;
    if (i < cnt) { unsigned p = bp[i]; s = (int)(p & 0x1FFFFu); dl = (int)(p >> 17) & 63; rk = atomicAdd(&hist[dl], 1); }
    mySrc[j] = s; myDl[j] = dl; myRk[j] = rk;
  }
  int ovn = *ovCount;                       // normally 0
  for (int i = tid; i < ovn; i += 256) {
    uint2 p = ovList[i];
    if (((int)p.y >> 6) == b) {
      int dl = (int)p.y & 63;
      int rk = atomicAdd(&hist[dl], 1);
      int li = atomicAdd(&ovLocN, 1);
      if (li < 64) ovLoc[li] = make_uint2(p.x, (unsigned)((rk << 8) | dl));
    }
  }
  __syncthreads();

  if (tid < 64) {
    int v = hist[tid];
    int padLen = (v + 1 + 7) & ~7;           // self-loop + edges, padded to multiple of 8
    int x = padLen;
    #pragma unroll
    for (int o = 1; o < 64; o <<= 1) { int t = __shfl_up(x, o); if (tid >= o) x += t; }
    int lo = x - padLen;                     // exclusive scan of padded lengths
    lofs[tid] = lo;
    int n = b * 64 + tid;
    if (n < Nn) {
      offsets[n] = b * SCAP + lo;
      deg[n] = padLen;
      buf[lo] = n;                           // self-loop in slot 0
    }
    if (tid == 63) totS = x;
  }
  __syncthreads();

  #pragma unroll
  for (int j = 0; j < 6; ++j) {
    if (mySrc[j] >= 0) {
      int pos = lofs[myDl[j]] + 1 + myRk[j];
      if (pos < SCAP) buf[pos] = mySrc[j];
    }
  }
  int ovl = ovLocN; if (ovl > 64) ovl = 64;
  for (int i = tid; i < ovl; i += 256) {
    uint2 p = ovLoc[i];
    int dl = (int)(p.y & 63), rk = (int)(p.y >> 8);
    int pos = lofs[dl] + 1 + rk;
    if (pos < SCAP) buf[pos] = (int)p.x;
  }
  __syncthreads();

  int tot = totS; if (tot > SCAP) tot = SCAP;
  for (int i = tid; i < tot; i += 256) sorted[(long)b * SCAP + i] = buf[i];
}

// ---------------- in_proj (LDS-staged, W hoisted to regs): h_bf = bf16(x @ W_in.T + b_in) ----------------
__global__ __launch_bounds__(512) void k_inproj(
    const float* __restrict__ A, const __hip_bfloat16* __restrict__ W,
    const float* __restrict__ bias, __hip_bfloat16* __restrict__ Cbf)
{
  __shared__ __hip_bfloat16 sA[64 * IPROW];   // 33.8 KB
  int tid = threadIdx.x;
  int bn0 = blockIdx.x * 64;
  int lane = tid & 63;
  int w = tid >> 6;
  int wr = w >> 2, wc = w & 3;
  int d0 = wc * 32;
  int r = lane & 15, g = lane >> 4;

  // hoist W fragments into registers: global-load latency overlaps staging + barrier
  bf8 wf[2][8];
  #pragma unroll
  for (int ni = 0; ni < 2; ++ni)
    #pragma unroll
    for (int kk = 0; kk < 8; ++kk)
      wf[ni][kk] = *reinterpret_cast<const bf8*>(W + (long)(d0 + ni * 16 + r) * 256 + kk * 32 + g * 8);

  #pragma unroll
  for (int pass = 0; pass < 8; ++pass) {
    int idx = pass * 2048 + tid * 4;          // 512 thr x float4 = 2048 floats/pass
    int row = idx >> 8, col = idx & 255;
    int grow = bn0 + row; grow = grow < Nn ? grow : Nn - 1;
    float4 f = *reinterpret_cast<const float4*>(A + (long)grow * 256 + col);
    unsigned p0 = ((unsigned)f2bfu(f.y) << 16) | f2bfu(f.x);
    unsigned p1 = ((unsigned)f2bfu(f.w) << 16) | f2bfu(f.z);
    *reinterpret_cast<uint2*>(reinterpret_cast<unsigned short*>(sA) + row * IPROW + col) = make_uint2(p0, p1);
  }
  __syncthreads();

  f4 acc[2][2] = {};
  #pragma unroll
  for (int kk = 0; kk < 8; ++kk) {
    bf8 a[2];
    #pragma unroll
    for (int mi = 0; mi < 2; ++mi)
      a[mi] = *reinterpret_cast<const bf8*>(sA + (wr * 32 + mi * 16 + r) * IPROW + kk * 32 + g * 8);
    #pragma unroll
    for (int mi = 0; mi < 2; ++mi)
      #pragma unroll
      for (int ni = 0; ni < 2; ++ni)
        acc[mi][ni] = __builtin_amdgcn_mfma_f32_16x16x32_bf16(a[mi], wf[ni][kk], acc[mi][ni], 0, 0, 0);
  }
  int n0 = bn0 + wr * 32;
  #pragma unroll
  for (int mi = 0; mi < 2; ++mi) {
    int nb = n0 + mi * 16 + g * 4;
    #pragma unroll
    for (int ni = 0; ni < 2; ++ni) {
      int d = d0 + ni * 16 + r;
      #pragma unroll
      for (int q = 0; q < 4; ++q) {
        int n = nb + q;
        if (n < Nn) Cbf[(long)n * 128 + d] = __float2bfloat16(acc[mi][ni][q] + bias[d]);
      }
    }
  }
}

// ---------------- layer GEMM (LDS-staged, W hoisted): [xh_u8 | e] = h @ Wext.T ----------------
__global__ __launch_bounds__(640) void k_gat_gemm(
    const __hip_bfloat16* __restrict__ A,     // h_bf [Nn][128]
    const __hip_bfloat16* __restrict__ Wext,  // [144][128]
    unsigned char* __restrict__ xh,           // biased u8 messages: q = clamp(v)*QSCALE + 128
    float* __restrict__ e_src, float* __restrict__ e_dst)
{
  __shared__ __hip_bfloat16 sA[64 * GGROW];   // 17.4 KB
  int tid = threadIdx.x;
  int bn0 = blockIdx.x * 64;
  int lane = tid & 63;
  int w = tid >> 6;
  int wr = w / 5, wc = w % 5;
  int d0 = wc * 32;
  int r = lane & 15, g = lane >> 4;
  bool eTile = (wc == 4);

  // hoist W fragments (guard second tile: eTile's rows 144+ would be OOB)
  bf8 wf[2][4];
  #pragma unroll
  for (int kk = 0; kk < 4; ++kk)
    wf[0][kk] = *reinterpret_cast<const bf8*>(Wext + (long)(d0 + r) * 128 + kk * 32 + g * 8);
  if (!eTile) {
    #pragma unroll
    for (int kk = 0; kk < 4; ++kk)
      wf[1][kk] = *reinterpret_cast<const bf8*>(Wext + (long)(d0 + 16 + r) * 128 + kk * 32 + g * 8);
  }

  {   // stage 64x128 bf16 = 1024 x 16B units
    int row = tid >> 4, col = (tid & 15) * 8;
    int grow = bn0 + row; grow = grow < Nn ? grow : Nn - 1;
    uint4 v = *reinterpret_cast<const uint4*>(A + (long)grow * 128 + col);
    *reinterpret_cast<uint4*>(reinterpret_cast<unsigned short*>(sA) + row * GGROW + col) = v;
    if (tid < 384) {
      int u1 = 640 + tid;
      int row1 = u1 >> 4, col1 = (u1 & 15) * 8;
      int grow1 = bn0 + row1; grow1 = grow1 < Nn ? grow1 : Nn - 1;
      uint4 v1 = *reinterpret_cast<const uint4*>(A + (long)grow1 * 128 + col1);
      *reinterpret_cast<uint4*>(reinterpret_cast<unsigned short*>(sA) + row1 * GGROW + col1) = v1;
    }
  }
  __syncthreads();

  f4 acc[2][2] = {};
  #pragma unroll
  for (int kk = 0; kk < 4; ++kk) {
    bf8 a[2];
    #pragma unroll
    for (int mi = 0; mi < 2; ++mi)
      a[mi] = *reinterpret_cast<const bf8*>(sA + (wr * 32 + mi * 16 + r) * GGROW + kk * 32 + g * 8);
    #pragma unroll
    for (int mi = 0; mi < 2; ++mi) {
      acc[mi][0] = __builtin_amdgcn_mfma_f32_16x16x32_bf16(a[mi], wf[0][kk], acc[mi][0], 0, 0, 0);
      if (!eTile) acc[mi][1] = __builtin_amdgcn_mfma_f32_16x16x32_bf16(a[mi], wf[1][kk], acc[mi][1], 0, 0, 0);
    }
  }
  int n0 = bn0 + wr * 32;
  if (!eTile) {
    #pragma unroll
    for (int mi = 0; mi < 2; ++mi) {
      int nb = n0 + mi * 16 + g * 4;
      #pragma unroll
      for (int ni = 0; ni < 2; ++ni) {
        int d = d0 + ni * 16 + r;
        #pragma unroll
        for (int q = 0; q < 4; ++q) {
          int n = nb + q;
          if (n < Nn) {
            float v = fminf(fmaxf(acc[mi][ni][q], -4.f), 4.f);
            xh[(long)n * 128 + d] = (unsigned char)(int)(rintf(v * QSCALE) + 128.f);
          }
        }
      }
    }
  } else {
    #pragma unroll
    for (int mi = 0; mi < 2; ++mi) {
      int nb = n0 + mi * 16 + g * 4;
      #pragma unroll
      for (int q = 0; q < 4; ++q) {
        int n = nb + q;
        if (n < Nn) {
          float v = acc[mi][0][q];
          if (r < 8) e_src[n * 8 + r] = v;
          else       e_dst[n * 8 + (r - 8)] = v;
        }
      }
    }
  }
}

// ---------------- fused agg (r13 version): single pass, 16-edge unroll, batched load phases ----------------
__global__ __launch_bounds__(256) void k_gat_agg(
    const unsigned char* __restrict__ xh,
    const float* __restrict__ e_src, const float* __restrict__ e_dst,
    const int* __restrict__ offsets, const int* __restrict__ deg, const int* __restrict__ sorted,
    const float* __restrict__ gat_b, const float* __restrict__ ln_g, const float* __restrict__ ln_b,
    float* __restrict__ hOut, __hip_bfloat16* __restrict__ h_bf, int last)
{
  int wv = threadIdx.x >> 6;
  int lane = threadIdx.x & 63;
  int n = blockIdx.x * 4 + wv;
  if (n >= Nn) return;

  int lp = lane & 31, half = lane >> 5;
  int g4 = lp >> 2;                           // head (8 per half)
  int ig = lane & 3;                          // lane-in-group
  int beg = offsets[n], len = deg[n];         // len is a multiple of 8
  float edst = e_dst[n * 8 + g4];
  int base = lane & ~3;

  const unsigned* xq = (const unsigned*)xh;
  float sOwn = 0.f, b0 = 0.f, b1 = 0.f, b2 = 0.f, b3 = 0.f;

  int i = 0;
  for (; i + 16 <= len; i += 16) {
    int scA = sorted[beg + i + 2 * ig + half];
    int scB = sorted[beg + i + 8 + 2 * ig + half];
    float esA = e_src[scA * 8 + g4];
    float esB = e_src[scB * 8 + g4];
    float lA = esA + edst; lA = fmaxf(lA, 0.2f * lA);
    float lB = esB + edst; lB = fmaxf(lB, 0.2f * lB);
    float pA = __expf(lA), pB = __expf(lB);
    sOwn += pA + pB;
    float pT[8]; int scT[8];
    #pragma unroll
    for (int t = 0; t < 4; ++t) {
      pT[t]     = __shfl(pA, base + t);  scT[t]     = __shfl(scA, base + t);
      pT[4 + t] = __shfl(pB, base + t);  scT[4 + t] = __shfl(scB, base + t);
    }
    unsigned u[8];
    #pragma unroll
    for (int t = 0; t < 8; ++t) u[t] = xq[(unsigned)scT[t] * 32u + (unsigned)lp];
    #pragma unroll
    for (int t = 0; t < 8; ++t) {
      b0 += pT[t] * (float)(u[t] & 0xffu);
      b1 += pT[t] * (float)((u[t] >> 8) & 0xffu);
      b2 += pT[t] * (float)((u[t] >> 16) & 0xffu);
      b3 += pT[t] * (float)(u[t] >> 24);
    }
  }
  if (i < len) {                              // one trailing 8-block
    int scA = sorted[beg + i + 2 * ig + half];
    float esA = e_src[scA * 8 + g4];
    float lA = esA + edst; lA = fmaxf(lA, 0.2f * lA);
    float pA = __expf(lA);
    sOwn += pA;
    float pT[4]; int scT[4];
    #pragma unroll
    for (int t = 0; t < 4; ++t) { pT[t] = __shfl(pA, base + t); scT[t] = __shfl(scA, base + t); }
    unsigned u[4];
    #pragma unroll
    for (int t = 0; t < 4; ++t) u[t] = xq[(unsigned)scT[t] * 32u + (unsigned)lp];
    #pragma unroll
    for (int t = 0; t < 4; ++t) {
      b0 += pT[t] * (float)(u[t] & 0xffu);
      b1 += pT[t] * (float)((u[t] >> 8) & 0xffu);
      b2 += pT[t] * (float)((u[t] >> 16) & 0xffu);
      b3 += pT[t] * (float)(u[t] >> 24);
    }
  }

  sOwn += __shfl_xor(sOwn, 1);
  sOwn += __shfl_xor(sOwn, 2);
  sOwn += __shfl_xor(sOwn, 32);
  b0 += __shfl_xor(b0, 32); b1 += __shfl_xor(b1, 32);
  b2 += __shfl_xor(b2, 32); b3 += __shfl_xor(b3, 32);
  float inv = QINV / (sOwn + 1e-16f);

  int c0 = 4 * lp;
  float4 rb = *reinterpret_cast<const float4*>(gat_b + c0);
  uint2 r2 = ((const uint2*)h_bf)[(long)n * 32 + lp];
  float o0 = b0 * inv + rb.x + bflo(r2.x) - CBIAS;
  float o1 = b1 * inv + rb.y + bfhi(r2.x) - CBIAS;
  float o2 = b2 * inv + rb.z + bflo(r2.y) - CBIAS;
  float o3 = b3 * inv + rb.w + bfhi(r2.y) - CBIAS;

  float t = o0 + o1 + o2 + o3;
  #pragma unroll
  for (int off = 1; off < 32; off <<= 1) t += __shfl_xor(t, off);
  float mean = t * (1.f / 128.f);
  float d0 = o0 - mean, d1 = o1 - mean, d2 = o2 - mean, d3 = o3 - mean;
  float sq = d0 * d0 + d1 * d1 + d2 * d2 + d3 * d3;
  #pragma unroll
  for (int off = 1; off < 32; off <<= 1) sq += __shfl_xor(sq, off);
  float rstd = rsqrtf(sq * (1.f / 128.f) + 1e-5f);

  float4 g4v = *reinterpret_cast<const float4*>(ln_g + c0);
  float4 bb4 = *reinterpret_cast<const float4*>(ln_b + c0);
  float y0 = d0 * rstd * g4v.x + bb4.x;
  float y1 = d1 * rstd * g4v.y + bb4.y;
  float y2 = d2 * rstd * g4v.z + bb4.z;
  float y3 = d3 * rstd * g4v.w + bb4.w;

  if (half == 0) {
    if (last) *reinterpret_cast<float4*>(hOut + (long)n * 128 + c0) = make_float4(y0, y1, y2, y3);
    uint2 pk;
    pk.x = ((unsigned)f2bfu(y1) << 16) | f2bfu(y0);
    pk.y = ((unsigned)f2bfu(y3) << 16) | f2bfu(y2);
    ((uint2*)h_bf)[(long)n * 32 + lp] = pk;
  }
}

// ---------------- pooling: 256 blocks x 8 waves, uint4 rows, wave+LDS reduce ----------------
__global__ __launch_bounds__(512) void k_pool(const __hip_bfloat16* __restrict__ h_bf, float* __restrict__ pooledSum) {
  int tid = threadIdx.x;
  int wv = tid >> 6, lane = tid & 63;
  int sub = lane >> 4;          // which of 4 rows this wave-iteration
  int c16 = lane & 15;          // 16B chunk within row -> channels 8*c16 .. 8*c16+7
  const uint4* hq = (const uint4*)h_bf;   // row = 16 uint4

  float acc[8] = {};
  for (int row = blockIdx.x * 32 + wv * 4 + sub; row < Nn; row += 256 * 32) {
    uint4 v = hq[(long)row * 16 + c16];
    acc[0] += bflo(v.x); acc[1] += bfhi(v.x);
    acc[2] += bflo(v.y); acc[3] += bfhi(v.y);
    acc[4] += bflo(v.z); acc[5] += bfhi(v.z);
    acc[6] += bflo(v.w); acc[7] += bfhi(v.w);
  }
  #pragma unroll
  for (int j = 0; j < 8; ++j) { acc[j] += __shfl_xor(acc[j], 16); acc[j] += __shfl_xor(acc[j], 32); }

  __shared__ float red[8][128];
  if (lane < 16) {
    #pragma unroll
    for (int j = 0; j < 8; ++j) red[wv][c16 * 8 + j] = acc[j];
  }
  __syncthreads();
  if (tid < 128) {
    float s = 0.f;
    #pragma unroll
    for (int w2 = 0; w2 < 8; ++w2) s += red[w2][tid];
    atomicAdd(&pooledSum[tid], s);
  }
}

__global__ __launch_bounds__(128) void k_final(
    const float* __restrict__ pooledSum,
    const float* __restrict__ W_mu, const float* __restrict__ b_mu,
    const float* __restrict__ W_lv, const float* __restrict__ b_lv,
    float* __restrict__ mu_out, float* __restrict__ lv_out, float* __restrict__ pooled_out)
{
  int d = threadIdx.x;
  __shared__ float pm[128];
  float p = pooledSum[d] * (1.f / (float)Nn);
  pm[d] = p; pooled_out[d] = p;
  __syncthreads();
  float mu = b_mu[d], lv = b_lv[d];
  const float4* wm = reinterpret_cast<const float4*>(W_mu + d * 128);
  const float4* wl = reinterpret_cast<const float4*>(W_lv + d * 128);
  #pragma unroll 8
  for (int c = 0; c < 32; ++c) {
    float4 a = wm[c], b = wl[c];
    float4 p4 = *reinterpret_cast<const float4*>(pm + 4 * c);
    mu += a.x * p4.x + a.y * p4.y + a.z * p4.z + a.w * p4.w;
    lv += b.x * p4.x + b.y * p4.y + b.z * p4.z + b.w * p4.w;
  }
  mu_out[d] = mu; lv_out[d] = lv;
}

// ---------------- launch ----------------
extern "C" void kernel_launch(void* const* d_in, const int* in_sizes, int n_in,
                              void* d_out, int out_size, void* d_ws, size_t ws_size,
                              hipStream_t stream) {
  const float* x      = (const float*)d_in[0];
  const int*   ei     = (const int*)d_in[1];
  const float* W_in   = (const float*)d_in[2];
  const float* b_in   = (const float*)d_in[3];
  const float* gat_W  = (const float*)d_in[4];
  const float* att_src= (const float*)d_in[5];
  const float* att_dst= (const float*)d_in[6];
  const float* gat_b  = (const float*)d_in[7];
  const float* ln_g   = (const float*)d_in[8];
  const float* ln_b   = (const float*)d_in[9];
  const float* W_mu   = (const float*)d_in[10];
  const float* b_mu   = (const float*)d_in[11];
  const float* W_lv   = (const float*)d_in[12];
  const float* b_lv   = (const float*)d_in[13];

  float* out = (float*)d_out;
  float* mu_out = out;
  float* lv_out = out + 128;
  float* h      = out + 256;                       // [Nn x 128] final h lives in d_out
  float* pooled_out = out + 256 + (long)Nn * 128;

  const int* srcE = ei;
  const int* dstE = ei + Ee;

  char* wsb = (char*)d_ws;
  size_t o = 0;
  auto take = [&](size_t bytes) { void* p = wsb + o; o += (bytes + 255) & ~(size_t)255; return p; };
  __hip_bfloat16* h_bf   = (__hip_bfloat16*)take((long)Nn * 128 * 2);
  unsigned char*  xh_u8  = (unsigned char*)take((long)(Nn + 1) * 128);  // 12.8MB (+1 sentinel row); pairs aliases it
  unsigned*       pairs  = (unsigned*)xh_u8;
  float*          e_src  = (float*)take((long)(Nn + 1) * 8 * 4);        // +1 sentinel row (-1e30)
  float*          e_dst  = (float*)take((long)Nn * 8 * 4);
  int*            sorted = (int*)take((long)NB * SCAP * 4);             // 12.8MB padded segments
  int*            offsets= (int*)take((long)Nn * 4);
  int*            deg    = (int*)take((long)Nn * 4);
  int*            gCursor= (int*)take((long)NB * CSTRIDE * 4);
  int*            ovCount= (int*)take(256);
  uint2*          ovList = (uint2*)take(65536L * 8);
  float*          pooledSum = (float*)take(512);
  __hip_bfloat16* Win_bf = (__hip_bfloat16*)take(128L * 256 * 2);
  __hip_bfloat16* Wext   = (__hip_bfloat16*)take(4L * 144 * 128 * 2);
  (void)ws_size; (void)n_in; (void)in_sizes; (void)out_size;

  k_f32_to_bf16<<<64, 256, 0, stream>>>(W_in, Win_bf, 128L * 256);
  k_prepw<<<(4 * 144 * 128 + 255) / 256, 256, 0, stream>>>(gat_W, att_src, att_dst, Wext);

  // CSR build: bucket partition + per-bucket LDS counting sort (padded to x8)
  k_init<<<(NB * CSTRIDE + 255) / 256, 256, 0, stream>>>(gCursor, ovCount, pooledSum, e_src);
  k_bucket<<<(Ee + CBLK - 1) / CBLK, 256, 0, stream>>>(srcE, dstE, gCursor, pairs, ovCount, ovList);
  k_finesort<<<NB, 256, 0, stream>>>(pairs, gCursor, ovCount, ovList, sorted, offsets, deg);

  int gB = (Nn + 63) / 64;   // 1563
  k_inproj<<<gB, 512, 0, stream>>>(x, Win_bf, b_in, h_bf);

  for (int l = 0; l < 4; ++l) {
    k_gat_gemm<<<gB, 640, 0, stream>>>(h_bf, Wext + (long)l * 144 * 128, xh_u8, e_src, e_dst);
    k_gat_agg<<<(Nn + 3) / 4, 256, 0, stream>>>(xh_u8, e_src, e_dst, offsets, deg, sorted,
                                                gat_b + l * 128, ln_g + l * 128, ln_b + l * 128,
                                                h, h_bf, (l == 3) ? 1 : 0);
  }

  k_pool<<<256, 512, 0, stream>>>(h_bf, pooledSum);
  k_final<<<1, 128, 0, stream>>>(pooledSum, W_mu, b_mu, W_lv, b_lv, mu_out, lv_out, pooled_out);
}